// Round 1
// baseline (582.583 us; speedup 1.0000x reference)
//
#include <hip/hip_runtime.h>
#include <cstdint>

// ---------------------------------------------------------------------------
// AdaptiveMixing fused kernel set.
// Shapes: BT=8192 tokens, C=128, P=OP=32, QD=256, HID=64, TP=17408.
// Plan:
//   prep    : w2/w1/wo -> bf16 copies in ws; out <- bo (fp32) for atomic K-split
//   fused   : per-wg 16 tokens: LN -> h (MFMA) -> sm gen (MFMA) ->
//             loop 16 d-tiles(8 cols): cm gen (MFMA, N=16 tokens) -> LDS ->
//             channel-mix MFMA + gelu -> spatial MFMA + gelu -> y2(bf16) to ws
//   outproj : y2[8192,4096](bf16) @ wo^T -> atomicAdd into out (K split x4)
// MFMA 16x16x32_bf16 layouts (guide-verified):
//   A: lane m=lane&15, k=(lane>>4)*8+j ; B: lane n=lane&15, k=(lane>>4)*8+j
//   C/D: col=lane&15, row=(lane>>4)*4+i
// ---------------------------------------------------------------------------

typedef __bf16 bf16x8 __attribute__((ext_vector_type(8)));
typedef float  f32x4  __attribute__((ext_vector_type(4)));
typedef unsigned short ushort;
typedef ushort ushort8 __attribute__((ext_vector_type(8)));

#define TW 16     // tokens per workgroup (fused)
#define NDT 16    // d-tiles of width 8

__device__ __forceinline__ ushort f2b(float f) {
    union { float f; uint32_t u; } v; v.f = f;
    uint32_t u = v.u;
    u += 0x7fffu + ((u >> 16) & 1u);   // RNE
    return (ushort)(u >> 16);
}
__device__ __forceinline__ float gelu_exact(float x) {
    return 0.5f * x * (1.0f + erff(x * 0.70710678118654752440f));
}

// ---------------------------------------------------------------------------
__global__ void prep(const float* __restrict__ w2, const float* __restrict__ w1,
                     const float* __restrict__ wo, const float* __restrict__ bo,
                     ushort* __restrict__ w2b, ushort* __restrict__ w1b,
                     ushort* __restrict__ wob, float* __restrict__ out) {
    int i = blockIdx.x * 256 + threadIdx.x;          // 2,097,152 threads
    if (i < 1114112) w2b[i] = f2b(w2[i]);            // [17408][64]
    if (i < 16384)   w1b[i] = f2b(w1[i]);            // [64][256]
    if (i < 1048576) wob[i] = f2b(wo[i]);            // [256][4096]
    if (i < 2097152) out[i] = bo[i & 255];           // out init = bias
}

// ---------------------------------------------------------------------------
__launch_bounds__(512, 2)
__global__ void fused(const float* __restrict__ sampled, const float* __restrict__ query,
                      const float* __restrict__ ln_w, const float* __restrict__ ln_b,
                      const float* __restrict__ b1, const float* __restrict__ b2,
                      const float* __restrict__ m_beta, const float* __restrict__ s_beta,
                      const ushort* __restrict__ w2b, const ushort* __restrict__ w1b,
                      ushort* __restrict__ y2) {
    __shared__ ushort Hb[TW * 64];                 // h, bf16 [t][64]
    __shared__ ushort smT[TW * 32 * 32];           // sm, bf16 [t][o][p]
    __shared__ union { ushort pt[TW * 8 * 136]; ushort qn[TW * 264]; } U;
    __shared__ ushort g1s[TW * 8 * 32];            // gelu(y1), bf16 [t][dd][p]
    __shared__ float  mb_s[128];
    __shared__ float  sb_s[32];

    const int tid  = threadIdx.x;
    const int wv   = tid >> 6;          // wave 0..7
    const int lane = tid & 63;
    const int lq   = lane >> 4;         // quad
    const int ln16 = lane & 15;
    const int tok0 = blockIdx.x * TW;

    if (tid < 128) mb_s[tid] = m_beta[tid];
    else if (tid < 160) sb_s[tid - 128] = s_beta[tid - 128];

    // ---- step 1: LayerNorm, 2 tokens per wave; qn -> LDS (bf16, padded rows 264)
    for (int tt = 0; tt < 2; ++tt) {
        int t = wv * 2 + tt;
        const float* q = query + (size_t)(tok0 + t) * 256;
        float2 a = *(const float2*)(q + 2 * lane);
        float2 b = *(const float2*)(q + 128 + 2 * lane);
        float s = a.x + a.y + b.x + b.y;
        for (int off = 1; off < 64; off <<= 1) s += __shfl_xor(s, off);
        float mu = s * (1.0f / 256.0f);
        float d0 = a.x - mu, d1 = a.y - mu, d2 = b.x - mu, d3 = b.y - mu;
        float ss = d0 * d0 + d1 * d1 + d2 * d2 + d3 * d3;
        for (int off = 1; off < 64; off <<= 1) ss += __shfl_xor(ss, off);
        float rstd = rsqrtf(ss * (1.0f / 256.0f) + 1e-6f);
        int i0 = 2 * lane, i1 = 2 * lane + 128;
        float q0 = d0 * rstd * ln_w[i0]     + ln_b[i0];
        float q1 = d1 * rstd * ln_w[i0 + 1] + ln_b[i0 + 1];
        float q2 = d2 * rstd * ln_w[i1]     + ln_b[i1];
        float q3 = d3 * rstd * ln_w[i1 + 1] + ln_b[i1 + 1];
        *(uint32_t*)&U.qn[t * 264 + i0] = (uint32_t)f2b(q0) | ((uint32_t)f2b(q1) << 16);
        *(uint32_t*)&U.qn[t * 264 + i1] = (uint32_t)f2b(q2) | ((uint32_t)f2b(q3) << 16);
    }
    __syncthreads();

    // ---- step 2: h[16 tok][64] = qn @ w1^T + b1 (waves 0..3, one n-block each)
    if (wv < 4) {
        int nb = wv;
        f32x4 acc = {0.0f, 0.0f, 0.0f, 0.0f};
        for (int ks = 0; ks < 8; ++ks) {
            bf16x8 afr = *(const bf16x8*)&U.qn[ln16 * 264 + ks * 32 + lq * 8];
            bf16x8 bfr = *(const bf16x8*)&w1b[(nb * 16 + ln16) * 256 + ks * 32 + lq * 8];
            acc = __builtin_amdgcn_mfma_f32_16x16x32_bf16(afr, bfr, acc, 0, 0, 0);
        }
        float bias = b1[nb * 16 + ln16];
        for (int i = 0; i < 4; ++i) {
            int t = lq * 4 + i;                      // D row = token
            Hb[t * 64 + nb * 16 + ln16] = f2b(acc[i] + bias);
        }
    }
    __syncthreads();

    // ---- step 3: gen B-frags (H), sm generation, x A-frag hoist
    bf16x8 hfr[2];
    hfr[0] = *(const bf16x8*)&Hb[ln16 * 64 + 0 + lq * 8];
    hfr[1] = *(const bf16x8*)&Hb[ln16 * 64 + 32 + lq * 8];

    for (int gi = 0; gi < 8; ++gi) {                 // sm rows 16384 + g*16 + m
        int g = wv * 8 + gi;
        int rbase = 16384 + g * 16;
        f32x4 acc = *(const f32x4*)&b2[rbase + lq * 4];   // bias init (4 consec rows)
        for (int ks = 0; ks < 2; ++ks) {
            bf16x8 afr = *(const bf16x8*)&w2b[(size_t)(rbase + ln16) * 64 + ks * 32 + lq * 8];
            acc = __builtin_amdgcn_mfma_f32_16x16x32_bf16(afr, hfr[ks], acc, 0, 0, 0);
        }
        int o = g >> 1;
        int p0 = (g & 1) * 16 + lq * 4;
        uint2 wr;
        wr.x = (uint32_t)f2b(acc[0]) | ((uint32_t)f2b(acc[1]) << 16);
        wr.y = (uint32_t)f2b(acc[2]) | ((uint32_t)f2b(acc[3]) << 16);
        *(uint2*)&smT[ln16 * 1024 + o * 32 + p0] = wr;   // token = D col
    }

    bf16x8 xa[2][2][4];                              // x A-frags [tt][p-half][ks]
    for (int tt = 0; tt < 2; ++tt) {
        const float* xp = sampled + (size_t)(tok0 + wv * 2 + tt) * 4096;
        for (int mt = 0; mt < 2; ++mt) {
            int p = mt * 16 + ln16;
            for (int ks = 0; ks < 4; ++ks) {
                int c = ks * 32 + lq * 8;
                float4 lo = *(const float4*)(xp + p * 128 + c);
                float4 hi = *(const float4*)(xp + p * 128 + c + 4);
                ushort8 u;
                u[0] = f2b(lo.x); u[1] = f2b(lo.y); u[2] = f2b(lo.z); u[3] = f2b(lo.w);
                u[4] = f2b(hi.x); u[5] = f2b(hi.y); u[6] = f2b(hi.z); u[7] = f2b(hi.w);
                xa[tt][mt][ks] = __builtin_bit_cast(bf16x8, u);
            }
        }
    }
    __syncthreads();

    // ---- step 4: sm A-frags for this wave's 2 tokens (K=32 -> single frag per o-half)
    bf16x8 sa[2][2];
    for (int tt = 0; tt < 2; ++tt) {
        int t = wv * 2 + tt;
        for (int mt = 0; mt < 2; ++mt)
            sa[tt][mt] = *(const bf16x8*)&smT[t * 1024 + (mt * 16 + ln16) * 32 + lq * 8];
    }

    // ---- main loop over 16 d-tiles of width 8
    for (int dt = 0; dt < NDT; ++dt) {
        int dbase = dt * 8;
        // GEN: wave wv owns c-block cb=wv; rows r = (cb*16+m)*128 + d
        int cb = wv;
        for (int dd = 0; dd < 8; ++dd) {
            int rb = (cb * 16) * 128 + dbase + dd;
            f32x4 acc;
            acc[0] = b2[rb + (lq * 4 + 0) * 128];
            acc[1] = b2[rb + (lq * 4 + 1) * 128];
            acc[2] = b2[rb + (lq * 4 + 2) * 128];
            acc[3] = b2[rb + (lq * 4 + 3) * 128];
            for (int ks = 0; ks < 2; ++ks) {
                bf16x8 afr = *(const bf16x8*)&w2b[(size_t)(rb + ln16 * 128) * 64 + ks * 32 + lq * 8];
                acc = __builtin_amdgcn_mfma_f32_16x16x32_bf16(afr, hfr[ks], acc, 0, 0, 0);
            }
            int c0 = cb * 16 + lq * 4;
            uint2 wr;
            wr.x = (uint32_t)f2b(acc[0]) | ((uint32_t)f2b(acc[1]) << 16);
            wr.y = (uint32_t)f2b(acc[2]) | ((uint32_t)f2b(acc[3]) << 16);
            *(uint2*)&U.pt[ln16 * 1088 + dd * 136 + c0] = wr;  // Pt[t][dd][c]
        }
        __syncthreads();

        // CONSUME: 2 tokens per wave
        for (int tt = 0; tt < 2; ++tt) {
            int t = wv * 2 + tt;
            int tok = tok0 + t;
            int ddl = ln16 & 7;                       // n>=8 lanes duplicate n-8
            bf16x8 bfr[4];
            for (int ks = 0; ks < 4; ++ks)
                bfr[ks] = *(const bf16x8*)&U.pt[t * 1088 + ddl * 136 + ks * 32 + lq * 8];
            // channel mix + gelu -> g1s
            for (int mt = 0; mt < 2; ++mt) {
                f32x4 acc = {0.0f, 0.0f, 0.0f, 0.0f};
                for (int ks = 0; ks < 4; ++ks)
                    acc = __builtin_amdgcn_mfma_f32_16x16x32_bf16(xa[tt][mt][ks], bfr[ks], acc, 0, 0, 0);
                float mb = mb_s[dbase + ddl];
                float g0 = gelu_exact(acc[0] + mb);
                float g1 = gelu_exact(acc[1] + mb);
                float g2 = gelu_exact(acc[2] + mb);
                float g3 = gelu_exact(acc[3] + mb);
                int p0 = mt * 16 + lq * 4;
                uint2 wr;
                wr.x = (uint32_t)f2b(g0) | ((uint32_t)f2b(g1) << 16);
                wr.y = (uint32_t)f2b(g2) | ((uint32_t)f2b(g3) << 16);
                *(uint2*)&g1s[t * 256 + ddl * 32 + p0] = wr;   // benign dup-write race
            }
            // spatial mix + gelu -> y2 (same wave: in-order LDS, no barrier needed)
            bf16x8 gb = *(const bf16x8*)&g1s[t * 256 + ddl * 32 + lq * 8];
            for (int mt = 0; mt < 2; ++mt) {
                f32x4 acc = {0.0f, 0.0f, 0.0f, 0.0f};
                acc = __builtin_amdgcn_mfma_f32_16x16x32_bf16(sa[tt][mt], gb, acc, 0, 0, 0);
                if (ln16 < 8) {
                    int d = dbase + ddl;
                    for (int i = 0; i < 4; ++i) {
                        int o = mt * 16 + lq * 4 + i;
                        y2[(size_t)tok * 4096 + o * 128 + d] = f2b(gelu_exact(acc[i] + sb_s[o]));
                    }
                }
            }
        }
        __syncthreads();
    }
}

// ---------------------------------------------------------------------------
__launch_bounds__(512, 2)
__global__ void outproj(const ushort* __restrict__ y2, const ushort* __restrict__ wob,
                        float* __restrict__ out) {
    int mb = blockIdx.x & 63;          // 64 M-blocks of 128 tokens
    int kc = blockIdx.x >> 6;          // 4 K-chunks of 1024
    int tid = threadIdx.x;
    int wv = tid >> 6, lane = tid & 63, lq = lane >> 4, ln16 = lane & 15;
    int wm = wv >> 2, wn = wv & 3;     // wave tile 64(m) x 64(n)
    int m0 = mb * 128 + wm * 64;
    int n0 = wn * 64;
    int k0 = kc * 1024;

    f32x4 zero = {0.0f, 0.0f, 0.0f, 0.0f};
    f32x4 acc[4][4];
    for (int mt = 0; mt < 4; ++mt)
        for (int nt = 0; nt < 4; ++nt) acc[mt][nt] = zero;

    for (int it = 0; it < 32; ++it) {
        int kk = k0 + it * 32;
        bf16x8 af[4], bf[4];
        for (int mt = 0; mt < 4; ++mt)
            af[mt] = *(const bf16x8*)&y2[(size_t)(m0 + mt * 16 + ln16) * 4096 + kk + lq * 8];
        for (int nt = 0; nt < 4; ++nt)
            bf[nt] = *(const bf16x8*)&wob[(size_t)(n0 + nt * 16 + ln16) * 4096 + kk + lq * 8];
        for (int mt = 0; mt < 4; ++mt)
            for (int nt = 0; nt < 4; ++nt)
                acc[mt][nt] = __builtin_amdgcn_mfma_f32_16x16x32_bf16(af[mt], bf[nt], acc[mt][nt], 0, 0, 0);
    }
    for (int mt = 0; mt < 4; ++mt)
        for (int nt = 0; nt < 4; ++nt)
            for (int i = 0; i < 4; ++i) {
                int tok = m0 + mt * 16 + lq * 4 + i;
                int q   = n0 + nt * 16 + ln16;
                atomicAdd(&out[(size_t)tok * 256 + q], acc[mt][nt][i]);
            }
}

// ---------------------------------------------------------------------------
extern "C" void kernel_launch(void* const* d_in, const int* in_sizes, int n_in,
                              void* d_out, int out_size, void* d_ws, size_t ws_size,
                              hipStream_t stream) {
    const float* sampled = (const float*)d_in[0];
    const float* query   = (const float*)d_in[1];
    const float* ln_w    = (const float*)d_in[2];
    const float* ln_b    = (const float*)d_in[3];
    const float* w1      = (const float*)d_in[4];
    const float* b1      = (const float*)d_in[5];
    const float* w2      = (const float*)d_in[6];
    const float* b2      = (const float*)d_in[7];
    const float* m_beta  = (const float*)d_in[8];
    const float* s_beta  = (const float*)d_in[9];
    const float* wo      = (const float*)d_in[10];
    const float* bo      = (const float*)d_in[11];
    float* out = (float*)d_out;

    char* ws = (char*)d_ws;
    ushort* w2b = (ushort*)(ws);                    // 2,228,224 B
    ushort* wob = (ushort*)(ws + 2228224);          // 2,097,152 B
    ushort* w1b = (ushort*)(ws + 4325376);          //    32,768 B
    ushort* y2  = (ushort*)(ws + 4358144);          // 67,108,864 B  (total ~71.5 MB)

    prep<<<8192, 256, 0, stream>>>(w2, w1, wo, bo, w2b, w1b, wob, out);
    fused<<<512, 512, 0, stream>>>(sampled, query, ln_w, ln_b, b1, b2,
                                   m_beta, s_beta, w2b, w1b, y2);
    outproj<<<256, 512, 0, stream>>>(y2, wob, out);
}